// Round 14
// baseline (227.468 us; speedup 1.0000x reference)
//
#include <hip/hip_runtime.h>
#include <hip/hip_bf16.h>

typedef __bf16 bf16;
typedef __bf16 bf16x8 __attribute__((ext_vector_type(8)));
typedef __bf16 bf16x4 __attribute__((ext_vector_type(4)));
typedef float  f32x4  __attribute__((ext_vector_type(4)));

#define MFMA16(a,b,c) __builtin_amdgcn_mfma_f32_16x16x32_bf16((a),(b),(c),0,0,0)

__device__ __forceinline__ void gld16(const void* g, void* l) {
    __builtin_amdgcn_global_load_lds(
        (const __attribute__((address_space(1))) void*)g,
        (__attribute__((address_space(3))) void*)l, 16, 0, 0);
}

// Problem sizes: B=512, T=256, C=512, H=64
// ws layout: WTfrag [16 KC][12 nf][64 lane][8] bf16 @ 0  (196,608 bytes)

// ---- kernel 0: build pre-fragmented WT --------------------------------------
// WTfrag byte addr (KC*12+nf)*1024 + l*16 holds B-frag: 8 bf16 =
//   W_mat[k = KC*32 + (l>>4)*8 + j][col = (nf&3)*16 + (l&15)],  mat = nf>>2.
__global__ void __launch_bounds__(256) wt_frag_kernel(
        const float* __restrict__ Wq, const float* __restrict__ Wk,
        const float* __restrict__ Wv, bf16* __restrict__ WTfrag) {
    int tid = blockIdx.x * 256 + threadIdx.x;     // 98304 total
    int j  = tid & 7;
    int l  = (tid >> 3) & 63;
    int f  = tid >> 9;            // 0..767 = KC*12 + nf
    int nf = f % 12;
    int KC = f / 12;
    int k   = KC * 32 + (l >> 4) * 8 + j;
    int col = (nf & 3) * 16 + (l & 15);
    const float* W = (nf < 4) ? Wq : ((nf < 8) ? Wk : Wv);
    WTfrag[tid] = (bf16)W[k * 64 + col];
}

// ---- fused kernel: WAVE-SPECIALIZED proj + flash attention ------------------
// grid 256, 512 threads (8 waves), 1 block/CU, LDS 132096 B, 2 batches/block.
// *** R14 = R13 with __launch_bounds__(512, 1): HIP's 2nd arg is min BLOCKS/CU;
// hipcc converts to waves/EU = k*(B/64)/4. k=2 @512thr meant 4 waves/EU ->
// VGPR cap 128 -> acc[4][12] (192 regs) spilled -> R13's 226us. k=1 -> cap 256.
// Waves 0-3 = COMPUTERS (acc[4][12], zero global loads in phase 1);
// waves 4-7 = STAGERS (gld16 only, tiny live set). Per chunk: stagers issue
// k+1 while computers do k; ONE __syncthreads joins (stagers drain their own
// vmcnt there -> producer/consumer, HBM never idles in phase 1).
// LDS: x p0 @0 (32K) | x p1 @32768 (32K) | wt p0 @65536 (12K) | wt p1 @77824
//      (12K) | V @90112 (32K) | Pl @122880 (9216).  K reuses x p1 @32768.
// Cross-batch: during batch-0 scatter/attention, stagers pre-stage batch-1
// chunk 0 -> x p0 + wt p0 (both dead then); drained at the scatter barrier.
__global__ void __launch_bounds__(512, 1) fused_kernel(
        const float* __restrict__ x, const bf16* __restrict__ WTfrag,
        float* __restrict__ out) {
    extern __shared__ char smem[];

    const int tid  = threadIdx.x;
    const int l    = tid & 63;
    const int w    = tid >> 6;           // 0..7
    const bool comp = (w < 4);           // computers: waves 0-3
    const int wc   = w;                  // computer wave index (when comp)
    const int stid = tid & 255;          // stager linear id 0..255 (when !comp)
    const int lo   = l & 15;
    const int hi   = l >> 4;
    const char* xb0 = (const char*)x + (size_t)(2 * blockIdx.x) * 524288;
    const char* wb  = (const char*)WTfrag;

    // stager helpers
    auto stage_x = [&](const char* xb, int kc, int p) {
        #pragma unroll
        for (int j = 0; j < 8; ++j) {            // 2048 16B-units, 8/thread
            const int s   = j * 256 + stid;
            const int row = s >> 3;
            const int uL  = (s & 7) ^ (row & 7); // inverse-swizzle on SOURCE
            gld16(xb + (size_t)row * 2048 + kc * 128 + uL * 16,
                  smem + p * 32768 + s * 16);
        }
    };
    auto stage_wt = [&](int kc, int p) {
        #pragma unroll
        for (int j = 0; j < 3; ++j) {            // 768 16B-units, 3/thread
            const int s = j * 256 + stid;
            gld16(wb + kc * 12288 + s * 16, smem + 65536 + p * 12288 + s * 16);
        }
    };

    #pragma unroll 1
    for (int bt = 0; bt < 2; ++bt) {
        const char* xb = xb0 + (size_t)bt * 524288;

        // ---------------- phase 1: projection ----------------
        f32x4 acc[4][12];                        // [mq][nf] (computers only)
        #pragma unroll
        for (int mq = 0; mq < 4; ++mq)
            #pragma unroll
            for (int nf = 0; nf < 12; ++nf)
                acc[mq][nf] = (f32x4){0.f, 0.f, 0.f, 0.f};

        if (bt == 0) {                           // batch-1 chunk 0 pre-staged
            if (!comp) { stage_x(xb, 0, 0); stage_wt(0, 0); }
            __syncthreads();                     // chunk 0 landed
        }

        #pragma unroll 1
        for (int kc = 0; kc < 16; ++kc) {
            if (!comp) {
                if (kc < 15) {                   // issue k+1 during compute(k)
                    stage_x(xb, kc + 1, (kc + 1) & 1);
                    stage_wt(kc + 1, (kc + 1) & 1);
                }
            } else {
                const char* xlds  = smem + (kc & 1) * 32768;
                const char* wtlds = smem + 65536 + (kc & 1) * 12288;
                #pragma unroll
                for (int mq = 0; mq < 4; ++mq) {
                    const int row = mq * 64 + wc * 16 + lo;  // row&7 == lo&7
                    const int u0  = (hi * 2)     ^ (lo & 7);
                    const int u1  = (hi * 2 + 1) ^ (lo & 7);
                    f32x4 v0 = *(const f32x4*)(xlds + row * 128 + u0 * 16);
                    f32x4 v1 = *(const f32x4*)(xlds + row * 128 + u1 * 16);
                    bf16x8 a;
                    a[0] = (bf16)v0[0]; a[1] = (bf16)v0[1];
                    a[2] = (bf16)v0[2]; a[3] = (bf16)v0[3];
                    a[4] = (bf16)v1[0]; a[5] = (bf16)v1[1];
                    a[6] = (bf16)v1[2]; a[7] = (bf16)v1[3];
                    #pragma unroll
                    for (int nf = 0; nf < 12; ++nf) {
                        bf16x8 bf_ = *(const bf16x8*)(wtlds + nf * 1024 + l * 16);
                        acc[mq][nf] = MFMA16(a, bf_, acc[mq][nf]);
                    }
                }
            }
            __syncthreads();  // joins: drains stagers' k+1 issues; frees bufs
        }

        // ---------------- phase 2: K,V -> LDS; Q -> regs ----------------
        char* Kb = smem + 32768;                 // reuses x p1 (dead)
        char* Vb = smem + 90112;
        if (!comp) {
            if (bt == 0) {                       // pre-stage batch-1 chunk 0
                stage_x(xb + 524288, 0, 0);      // -> x p0 (dead)
                stage_wt(0, 0);                  // -> wt p0 (dead)
            }
        } else {
            #pragma unroll
            for (int nf = 4; nf < 12; ++nf) {
                #pragma unroll
                for (int mq = 0; mq < 4; ++mq) {
                    #pragma unroll
                    for (int i = 0; i < 4; ++i) {
                        bf16 v = (bf16)acc[mq][nf][i];
                        if (nf < 8) {
                            const int row = mq * 64 + wc * 16 + hi * 4 + i;
                            const int col = (nf - 4) * 16 + lo;
                            const int u   = col >> 3;
                            *(bf16*)(Kb + row * 128 + ((u ^ (row & 7)) << 4) +
                                     (col & 7) * 2) = v;
                        } else {
                            const int hh = (nf - 8) * 16 + lo;
                            const int t  = mq * 64 + wc * 16 + hi * 4 + i;
                            const int u  = t >> 3;
                            *(bf16*)(Vb + hh * 512 + ((u ^ (hh & 7)) << 4) +
                                     (t & 7) * 2) = v;
                        }
                    }
                }
            }
        }
        __syncthreads();     // scatter visible; batch-1 chunk 0 drained (bt=0)

        if (comp) {
            // Q transpose: wave-PRIVATE Pl -> same-wave ds_write->ds_read
            // ordered by compiler lgkmcnt
            bf16* Pl = (bf16*)(smem + 122880) + wc * 1152;   // [16][72]
            bf16x8 qfr[4][2];
            #pragma unroll
            for (int qf = 0; qf < 4; ++qf) {
                #pragma unroll
                for (int nf = 0; nf < 4; ++nf)
                    #pragma unroll
                    for (int i = 0; i < 4; ++i)
                        Pl[(hi * 4 + i) * 72 + nf * 16 + lo] = (bf16)acc[qf][nf][i];
                #pragma unroll
                for (int ks = 0; ks < 2; ++ks)
                    qfr[qf][ks] = *(const bf16x8*)(Pl + lo * 72 + ks * 32 + hi * 8);
            }

            // ---------------- phase 3: causal flash attention ------------
            f32x4 o[4][4];
            #pragma unroll
            for (int qf = 0; qf < 4; ++qf)
                #pragma unroll
                for (int mf = 0; mf < 4; ++mf)
                    o[qf][mf] = (f32x4){0.f, 0.f, 0.f, 0.f};
            float m2[4]   = {-INFINITY, -INFINITY, -INFINITY, -INFINITY};
            float lsum[4] = {0.f, 0.f, 0.f, 0.f};
            const float SC = 0.125f * 1.44269504088896340736f; // scale*log2e

            #pragma unroll
            for (int kc = 0; kc < 4; ++kc) {
                bf16x8 vf[4][2];
                #pragma unroll
                for (int mf = 0; mf < 4; ++mf)
                    #pragma unroll
                    for (int ks = 0; ks < 2; ++ks) {
                        const int hh = mf * 16 + lo;        // hh&7 == lo&7
                        const int u  = kc * 8 + ks * 4 + hi;
                        vf[mf][ks] = *(const bf16x8*)(Vb + hh * 512 +
                                                      ((u ^ (lo & 7)) << 4));
                    }

                #pragma unroll
                for (int qf = kc; qf < 4; ++qf) {
                    f32x4 s[4];
                    #pragma unroll
                    for (int kf = 0; kf < 4; ++kf) {
                        const int key = kc * 64 + kf * 16 + lo;  // key&7==lo&7
                        bf16x8 k0 = *(const bf16x8*)(Kb + key * 128 +
                                        ((hi ^ (lo & 7)) << 4));
                        bf16x8 k1 = *(const bf16x8*)(Kb + key * 128 +
                                        (((4 + hi) ^ (lo & 7)) << 4));
                        f32x4 t = (f32x4){0.f, 0.f, 0.f, 0.f};
                        t = MFMA16(k0, qfr[qf][0], t);
                        t = MFMA16(k1, qfr[qf][1], t);
                        s[kf] = t;
                    }
                    float mx = -INFINITY;
                    #pragma unroll
                    for (int kf = 0; kf < 4; ++kf)
                        #pragma unroll
                        for (int i = 0; i < 4; ++i) {
                            float v = s[kf][i] * SC;
                            if (kc == qf && (kf * 16 + hi * 4 + i) > (wc * 16 + lo))
                                v = -INFINITY;
                            s[kf][i] = v;
                            mx = fmaxf(mx, v);
                        }
                    mx = fmaxf(mx, __shfl_xor(mx, 16));
                    mx = fmaxf(mx, __shfl_xor(mx, 32));
                    const float mnew = fmaxf(m2[qf], mx);
                    const float rsc  = exp2f(m2[qf] - mnew);
                    m2[qf] = mnew;

                    float cs = 0.f;
                    bf16x4 pk[4];
                    #pragma unroll
                    for (int kf = 0; kf < 4; ++kf)
                        #pragma unroll
                        for (int i = 0; i < 4; ++i) {
                            float p = exp2f(s[kf][i] - mnew);
                            cs += p;
                            pk[kf][i] = (bf16)p;
                        }
                    cs += __shfl_xor(cs, 16);
                    cs += __shfl_xor(cs, 32);
                    lsum[qf] = lsum[qf] * rsc + cs;

                    #pragma unroll
                    for (int kf = 0; kf < 4; ++kf)
                        *(bf16x4*)(Pl + lo * 72 + kf * 16 + hi * 4) = pk[kf];

                    #pragma unroll
                    for (int mf = 0; mf < 4; ++mf) {
                        o[qf][mf][0] *= rsc; o[qf][mf][1] *= rsc;
                        o[qf][mf][2] *= rsc; o[qf][mf][3] *= rsc;
                    }
                    #pragma unroll
                    for (int ks = 0; ks < 2; ++ks) {
                        bf16x8 pf = *(const bf16x8*)(Pl + lo * 72 + ks * 32 + hi * 8);
                        #pragma unroll
                        for (int mf = 0; mf < 4; ++mf)
                            o[qf][mf] = MFMA16(vf[mf][ks], pf, o[qf][mf]);
                    }
                }
            }

            // epilogue: out[bb][q][hcol] fp32, coalesced f32x4
            const int bb = 2 * blockIdx.x + bt;
            #pragma unroll
            for (int qf = 0; qf < 4; ++qf) {
                const float inv = 1.0f / lsum[qf];
                const int q = qf * 64 + wc * 16 + lo;
                #pragma unroll
                for (int mf = 0; mf < 4; ++mf) {
                    f32x4 r4;
                    r4[0] = o[qf][mf][0] * inv; r4[1] = o[qf][mf][1] * inv;
                    r4[2] = o[qf][mf][2] * inv; r4[3] = o[qf][mf][3] * inv;
                    *(f32x4*)(out + ((size_t)bb * 256 + q) * 64 + mf * 16 + hi * 4) = r4;
                }
            }
        }
        __syncthreads();   // protect K/V/Pl and x p1 from next batch's staging
    }
}

// ---- launcher ---------------------------------------------------------------
extern "C" void kernel_launch(void* const* d_in, const int* in_sizes, int n_in,
                              void* d_out, int out_size, void* d_ws, size_t ws_size,
                              hipStream_t stream) {
    const float* x  = (const float*)d_in[0];
    const float* Wq = (const float*)d_in[1];
    const float* Wk = (const float*)d_in[2];
    const float* Wv = (const float*)d_in[3];
    float* out = (float*)d_out;

    bf16* WTfrag = (bf16*)d_ws;

    wt_frag_kernel<<<dim3(384), dim3(256), 0, stream>>>(Wq, Wk, Wv, WTfrag);
    fused_kernel<<<dim3(256), dim3(512), 132096, stream>>>(x, WTfrag, out);
}

// Round 15
// 101.082 us; speedup vs baseline: 2.2503x; 2.2503x over previous
//
#include <hip/hip_runtime.h>
#include <hip/hip_bf16.h>

typedef __bf16 bf16;
typedef __bf16 bf16x8 __attribute__((ext_vector_type(8)));
typedef __bf16 bf16x4 __attribute__((ext_vector_type(4)));
typedef float  f32x4  __attribute__((ext_vector_type(4)));

#define MFMA16(a,b,c) __builtin_amdgcn_mfma_f32_16x16x32_bf16((a),(b),(c),0,0,0)

__device__ __forceinline__ void gld16(const void* g, void* l) {
    __builtin_amdgcn_global_load_lds(
        (const __attribute__((address_space(1))) void*)g,
        (__attribute__((address_space(3))) void*)l, 16, 0, 0);
}

// Problem sizes: B=512, T=256, C=512, H=64
// ws layout: WTfrag [16 KC][12 nf][64 lane][8] bf16 @ 0  (196,608 bytes)

// ---- kernel 0: build pre-fragmented WT --------------------------------------
// WTfrag byte addr (KC*12+nf)*1024 + l*16 holds B-frag: 8 bf16 =
//   W_mat[k = KC*32 + (l>>4)*8 + j][col = (nf&3)*16 + (l&15)],  mat = nf>>2.
__global__ void __launch_bounds__(256) wt_frag_kernel(
        const float* __restrict__ Wq, const float* __restrict__ Wk,
        const float* __restrict__ Wv, bf16* __restrict__ WTfrag) {
    int tid = blockIdx.x * 256 + threadIdx.x;     // 98304 total
    int j  = tid & 7;
    int l  = (tid >> 3) & 63;
    int f  = tid >> 9;            // 0..767 = KC*12 + nf
    int nf = f % 12;
    int KC = f / 12;
    int k   = KC * 32 + (l >> 4) * 8 + j;
    int col = (nf & 3) * 16 + (l & 15);
    const float* W = (nf < 4) ? Wq : ((nf < 8) ? Wk : Wv);
    WTfrag[tid] = (bf16)W[k * 64 + col];
}

// ---- fused kernel: proj + flash attention (R9 + relaxed reg budget) ---------
// grid 512 (block = batch), 256 threads (4 waves), LDS 74752 B.
// *** R15 = R9 byte-identical except __launch_bounds__(256, 1): relaxes the
// register-allocation budget (so the unified VGPR/AGPR file can hold the full
// 192-reg acc without a forced split/spill), while LDS (74752 B) still
// physically enforces 2 blocks/CU -> co-residency preserved by LDS, not by
// the bounds. Single-variable spill-hypothesis test vs R9's 71.8 us.
// Phase 1: 16 KC chunks; x single buf @0 (32KB, src-XOR-swizzled 16B units),
//          WT single buf @32768 (12KB). ALL sync via __syncthreads().
//          Wave w owns rows {mq*64 + w*16 + 0..15}.
// Phase 2: K,V acc -> swizzled LDS (K@0 [256][128B], VT@32768 [64][512B]);
//          Q transposed wave-locally via Pl @65536+w*2304 into registers.
// Phase 3: causal flash attention from LDS; out straight to HBM.
__global__ void __launch_bounds__(256, 1) fused_kernel(
        const float* __restrict__ x, const bf16* __restrict__ WTfrag,
        float* __restrict__ out) {
    extern __shared__ char smem[];

    const int tid = threadIdx.x;
    const int l   = tid & 63;
    const int w   = tid >> 6;
    const int lo  = l & 15;
    const int hi  = l >> 4;
    const int b   = blockIdx.x;
    const char* xb = (const char*)x + (size_t)b * 524288;   // 256 rows * 2048 B
    const char* wb = (const char*)WTfrag;

    // ---------------- phase 1: projection ----------------
    f32x4 acc[4][12];                        // [mq][nf]; 192 regs
    #pragma unroll
    for (int mq = 0; mq < 4; ++mq)
        #pragma unroll
        for (int nf = 0; nf < 12; ++nf)
            acc[mq][nf] = (f32x4){0.f, 0.f, 0.f, 0.f};

    #pragma unroll 1
    for (int kc = 0; kc < 16; ++kc) {
        // stage x chunk kc: 2048 16B-units, 8/thread (src-XOR-swizzled)
        #pragma unroll
        for (int j = 0; j < 8; ++j) {
            const int s   = j * 256 + tid;
            const int row = s >> 3;
            const int uP  = s & 7;
            const int uL  = uP ^ (row & 7);  // inverse-swizzle on SOURCE
            gld16(xb + (size_t)row * 2048 + kc * 128 + uL * 16,
                  smem + s * 16);
        }
        // stage WT chunk kc: 12 KB verbatim, 3/thread
        #pragma unroll
        for (int j = 0; j < 3; ++j) {
            const int s = j * 256 + tid;
            gld16(wb + kc * 12288 + s * 16, smem + 32768 + s * 16);
        }
        __syncthreads();                     // vmcnt(0) drain: chunk kc landed

        bf16x8 a[4];
        #pragma unroll
        for (int mq = 0; mq < 4; ++mq) {
            const int row = mq * 64 + w * 16 + lo;      // row&7 == lo&7
            const int u0  = (hi * 2)     ^ (lo & 7);
            const int u1  = (hi * 2 + 1) ^ (lo & 7);
            f32x4 v0 = *(const f32x4*)(smem + row * 128 + u0 * 16);
            f32x4 v1 = *(const f32x4*)(smem + row * 128 + u1 * 16);
            bf16x8 t;
            t[0] = (bf16)v0[0]; t[1] = (bf16)v0[1]; t[2] = (bf16)v0[2]; t[3] = (bf16)v0[3];
            t[4] = (bf16)v1[0]; t[5] = (bf16)v1[1]; t[6] = (bf16)v1[2]; t[7] = (bf16)v1[3];
            a[mq] = t;
        }
        #pragma unroll
        for (int nf = 0; nf < 12; ++nf) {
            bf16x8 bf_ = *(const bf16x8*)(smem + 32768 + nf * 1024 + l * 16);
            #pragma unroll
            for (int mq = 0; mq < 4; ++mq)
                acc[mq][nf] = MFMA16(a[mq], bf_, acc[mq][nf]);
        }
        __syncthreads();                     // all waves done reading bufs
    }

    // ---------------- phase 2: K,V -> LDS; Q -> regs ----------------
    char* Kb = smem;
    char* Vb = smem + 32768;
    #pragma unroll
    for (int nf = 4; nf < 12; ++nf) {
        #pragma unroll
        for (int mq = 0; mq < 4; ++mq) {
            #pragma unroll
            for (int i = 0; i < 4; ++i) {
                bf16 v = (bf16)acc[mq][nf][i];
                if (nf < 8) {
                    const int row = mq * 64 + w * 16 + hi * 4 + i;
                    const int col = (nf - 4) * 16 + lo;
                    const int u   = col >> 3;
                    *(bf16*)(Kb + row * 128 + ((u ^ (row & 7)) << 4) +
                             (col & 7) * 2) = v;
                } else {
                    const int h = (nf - 8) * 16 + lo;
                    const int t = mq * 64 + w * 16 + hi * 4 + i;
                    const int u = t >> 3;
                    *(bf16*)(Vb + h * 512 + ((u ^ (h & 7)) << 4) +
                             (t & 7) * 2) = v;
                }
            }
        }
    }

    // Q: acc[qf][0..3] -> qfr via per-wave LDS transpose ([16][72] @65536+w*2304)
    bf16* Pl = (bf16*)(smem + 65536) + w * 1152;
    bf16x8 qfr[4][2];
    #pragma unroll
    for (int qf = 0; qf < 4; ++qf) {
        #pragma unroll
        for (int nf = 0; nf < 4; ++nf)
            #pragma unroll
            for (int i = 0; i < 4; ++i)
                Pl[(hi * 4 + i) * 72 + nf * 16 + lo] = (bf16)acc[qf][nf][i];
        __syncthreads();                     // writes visible
        #pragma unroll
        for (int ks = 0; ks < 2; ++ks)
            qfr[qf][ks] = *(const bf16x8*)(Pl + lo * 72 + ks * 32 + hi * 8);
        __syncthreads();                     // reads done before next overwrite
    }

    // ---------------- phase 3: causal flash attention ----------------
    f32x4 o[4][4];
    #pragma unroll
    for (int qf = 0; qf < 4; ++qf)
        #pragma unroll
        for (int mf = 0; mf < 4; ++mf)
            o[qf][mf] = (f32x4){0.f, 0.f, 0.f, 0.f};
    float m2[4]   = {-INFINITY, -INFINITY, -INFINITY, -INFINITY};
    float lsum[4] = {0.f, 0.f, 0.f, 0.f};

    const float SC = 0.125f * 1.44269504088896340736f;  // scale * log2(e)

    #pragma unroll
    for (int kc = 0; kc < 4; ++kc) {
        bf16x8 vf[4][2];
        #pragma unroll
        for (int mf = 0; mf < 4; ++mf)
            #pragma unroll
            for (int ks = 0; ks < 2; ++ks) {
                const int h = mf * 16 + lo;             // h&7 == lo&7
                const int u = kc * 8 + ks * 4 + hi;
                vf[mf][ks] = *(const bf16x8*)(Vb + h * 512 + ((u ^ (lo & 7)) << 4));
            }

        #pragma unroll
        for (int qf = kc; qf < 4; ++qf) {
            f32x4 s[4];
            #pragma unroll
            for (int kf = 0; kf < 4; ++kf) {
                const int key = kc * 64 + kf * 16 + lo; // key&7 == lo&7
                bf16x8 k0 = *(const bf16x8*)(Kb + key * 128 + ((hi ^ (lo & 7)) << 4));
                bf16x8 k1 = *(const bf16x8*)(Kb + key * 128 + (((4 + hi) ^ (lo & 7)) << 4));
                f32x4 t = (f32x4){0.f, 0.f, 0.f, 0.f};
                t = MFMA16(k0, qfr[qf][0], t);
                t = MFMA16(k1, qfr[qf][1], t);
                s[kf] = t;
            }
            float mx = -INFINITY;
            #pragma unroll
            for (int kf = 0; kf < 4; ++kf)
                #pragma unroll
                for (int i = 0; i < 4; ++i) {
                    float v = s[kf][i] * SC;
                    if (kc == qf && (kf * 16 + hi * 4 + i) > (w * 16 + lo)) v = -INFINITY;
                    s[kf][i] = v;
                    mx = fmaxf(mx, v);
                }
            mx = fmaxf(mx, __shfl_xor(mx, 16));
            mx = fmaxf(mx, __shfl_xor(mx, 32));
            const float mnew = fmaxf(m2[qf], mx);
            const float rsc  = exp2f(m2[qf] - mnew);
            m2[qf] = mnew;

            float cs = 0.f;
            bf16x4 pk[4];
            #pragma unroll
            for (int kf = 0; kf < 4; ++kf)
                #pragma unroll
                for (int i = 0; i < 4; ++i) {
                    float p = exp2f(s[kf][i] - mnew);
                    cs += p;
                    pk[kf][i] = (bf16)p;
                }
            cs += __shfl_xor(cs, 16);
            cs += __shfl_xor(cs, 32);
            lsum[qf] = lsum[qf] * rsc + cs;

            #pragma unroll
            for (int kf = 0; kf < 4; ++kf)
                *(bf16x4*)(Pl + lo * 72 + kf * 16 + hi * 4) = pk[kf];

            #pragma unroll
            for (int mf = 0; mf < 4; ++mf) {
                o[qf][mf][0] *= rsc; o[qf][mf][1] *= rsc;
                o[qf][mf][2] *= rsc; o[qf][mf][3] *= rsc;
            }
            #pragma unroll
            for (int ks = 0; ks < 2; ++ks) {
                bf16x8 pf = *(const bf16x8*)(Pl + lo * 72 + ks * 32 + hi * 8);
                #pragma unroll
                for (int mf = 0; mf < 4; ++mf)
                    o[qf][mf] = MFMA16(vf[mf][ks], pf, o[qf][mf]);
            }
        }
    }

    // epilogue: out[b][q][h] fp32, coalesced f32x4
    #pragma unroll
    for (int qf = 0; qf < 4; ++qf) {
        const float inv = 1.0f / lsum[qf];
        const int q = qf * 64 + w * 16 + lo;
        #pragma unroll
        for (int mf = 0; mf < 4; ++mf) {
            f32x4 r4;
            r4[0] = o[qf][mf][0] * inv; r4[1] = o[qf][mf][1] * inv;
            r4[2] = o[qf][mf][2] * inv; r4[3] = o[qf][mf][3] * inv;
            *(f32x4*)(out + (b * 256 + q) * 64 + mf * 16 + hi * 4) = r4;
        }
    }
}

// ---- launcher ---------------------------------------------------------------
extern "C" void kernel_launch(void* const* d_in, const int* in_sizes, int n_in,
                              void* d_out, int out_size, void* d_ws, size_t ws_size,
                              hipStream_t stream) {
    const float* x  = (const float*)d_in[0];
    const float* Wq = (const float*)d_in[1];
    const float* Wk = (const float*)d_in[2];
    const float* Wv = (const float*)d_in[3];
    float* out = (float*)d_out;

    bf16* WTfrag = (bf16*)d_ws;

    wt_frag_kernel<<<dim3(384), dim3(256), 0, stream>>>(Wq, Wk, Wv, WTfrag);
    fused_kernel<<<dim3(512), dim3(256), 74752, stream>>>(x, WTfrag, out);
}

// Round 16
// 71.364 us; speedup vs baseline: 3.1874x; 1.4164x over previous
//
#include <hip/hip_runtime.h>
#include <hip/hip_bf16.h>

typedef __bf16 bf16;
typedef __bf16 bf16x8 __attribute__((ext_vector_type(8)));
typedef __bf16 bf16x4 __attribute__((ext_vector_type(4)));
typedef float  f32x4  __attribute__((ext_vector_type(4)));

#define MFMA16(a,b,c) __builtin_amdgcn_mfma_f32_16x16x32_bf16((a),(b),(c),0,0,0)

__device__ __forceinline__ void gld16(const void* g, void* l) {
    __builtin_amdgcn_global_load_lds(
        (const __attribute__((address_space(1))) void*)g,
        (__attribute__((address_space(3))) void*)l, 16, 0, 0);
}

// Problem sizes: B=512, T=256, C=512, H=64
// ws layout: WTfrag [16 KC][12 nf][64 lane][8] bf16 @ 0  (196,608 bytes)

// ---- kernel 0: build pre-fragmented WT --------------------------------------
// WTfrag byte addr (KC*12+nf)*1024 + l*16 holds B-frag: 8 bf16 =
//   W_mat[k = KC*32 + (l>>4)*8 + j][col = (nf&3)*16 + (l&15)],  mat = nf>>2.
__global__ void __launch_bounds__(256) wt_frag_kernel(
        const float* __restrict__ Wq, const float* __restrict__ Wk,
        const float* __restrict__ Wv, bf16* __restrict__ WTfrag) {
    int tid = blockIdx.x * 256 + threadIdx.x;     // 98304 total
    int j  = tid & 7;
    int l  = (tid >> 3) & 63;
    int f  = tid >> 9;            // 0..767 = KC*12 + nf
    int nf = f % 12;
    int KC = f / 12;
    int k   = KC * 32 + (l >> 4) * 8 + j;
    int col = (nf & 3) * 16 + (l & 15);
    const float* W = (nf < 4) ? Wq : ((nf < 8) ? Wk : Wv);
    WTfrag[tid] = (bf16)W[k * 64 + col];
}

// ---- fused kernel: proj + flash attention (R9 basin + safe tail cleanup) ----
// grid 512 (block = batch), 256 threads (4 waves), LDS 74752 B -> 2 blocks/CU.
// *** Phase 1 is BYTE-IDENTICAL to R9 (71.8us): (256,2) cap=256 fits the
// ~240-reg live set; 512-thr variants pin VGPR=128 (R13/R14), register B-frags
// or prefetch-before-compute spill (R10/R11), (256,1) loses co-residency
// (R15). Do not touch the hot loop.
// Cleanups vs R9 (outside hot loop): Q-transpose barrier-free (Pl wave-private,
// same-wave lgkmcnt ordering — proven R13/R14 + R9's own phase 3); ONE barrier
// after K/V scatter for cross-wave visibility; V-scatter uses bf16x4 stores.
__global__ void __launch_bounds__(256, 2) fused_kernel(
        const float* __restrict__ x, const bf16* __restrict__ WTfrag,
        float* __restrict__ out) {
    extern __shared__ char smem[];

    const int tid = threadIdx.x;
    const int l   = tid & 63;
    const int w   = tid >> 6;
    const int lo  = l & 15;
    const int hi  = l >> 4;
    const int b   = blockIdx.x;
    const char* xb = (const char*)x + (size_t)b * 524288;   // 256 rows * 2048 B
    const char* wb = (const char*)WTfrag;

    // ---------------- phase 1: projection (R9, untouched) ----------------
    f32x4 acc[4][12];                        // [mq][nf]; 192 regs
    #pragma unroll
    for (int mq = 0; mq < 4; ++mq)
        #pragma unroll
        for (int nf = 0; nf < 12; ++nf)
            acc[mq][nf] = (f32x4){0.f, 0.f, 0.f, 0.f};

    #pragma unroll 1
    for (int kc = 0; kc < 16; ++kc) {
        // stage x chunk kc: 2048 16B-units, 8/thread (src-XOR-swizzled)
        #pragma unroll
        for (int j = 0; j < 8; ++j) {
            const int s   = j * 256 + tid;
            const int row = s >> 3;
            const int uP  = s & 7;
            const int uL  = uP ^ (row & 7);  // inverse-swizzle on SOURCE
            gld16(xb + (size_t)row * 2048 + kc * 128 + uL * 16,
                  smem + s * 16);
        }
        // stage WT chunk kc: 12 KB verbatim, 3/thread
        #pragma unroll
        for (int j = 0; j < 3; ++j) {
            const int s = j * 256 + tid;
            gld16(wb + kc * 12288 + s * 16, smem + 32768 + s * 16);
        }
        __syncthreads();                     // vmcnt(0) drain: chunk kc landed

        bf16x8 a[4];
        #pragma unroll
        for (int mq = 0; mq < 4; ++mq) {
            const int row = mq * 64 + w * 16 + lo;      // row&7 == lo&7
            const int u0  = (hi * 2)     ^ (lo & 7);
            const int u1  = (hi * 2 + 1) ^ (lo & 7);
            f32x4 v0 = *(const f32x4*)(smem + row * 128 + u0 * 16);
            f32x4 v1 = *(const f32x4*)(smem + row * 128 + u1 * 16);
            bf16x8 t;
            t[0] = (bf16)v0[0]; t[1] = (bf16)v0[1]; t[2] = (bf16)v0[2]; t[3] = (bf16)v0[3];
            t[4] = (bf16)v1[0]; t[5] = (bf16)v1[1]; t[6] = (bf16)v1[2]; t[7] = (bf16)v1[3];
            a[mq] = t;
        }
        #pragma unroll
        for (int nf = 0; nf < 12; ++nf) {
            bf16x8 bf_ = *(const bf16x8*)(smem + 32768 + nf * 1024 + l * 16);
            #pragma unroll
            for (int mq = 0; mq < 4; ++mq)
                acc[mq][nf] = MFMA16(a[mq], bf_, acc[mq][nf]);
        }
        __syncthreads();                     // all waves done reading bufs
    }

    // ---------------- phase 2: K,V -> LDS; Q -> regs ----------------
    char* Kb = smem;
    char* Vb = smem + 32768;
    #pragma unroll
    for (int nf = 4; nf < 12; ++nf) {
        #pragma unroll
        for (int mq = 0; mq < 4; ++mq) {
            if (nf < 8) {
                #pragma unroll
                for (int i = 0; i < 4; ++i) {      // K: row varies with i
                    bf16 v = (bf16)acc[mq][nf][i];
                    const int row = mq * 64 + w * 16 + hi * 4 + i;
                    const int col = (nf - 4) * 16 + lo;
                    const int u   = col >> 3;
                    *(bf16*)(Kb + row * 128 + ((u ^ (row & 7)) << 4) +
                             (col & 7) * 2) = v;
                }
            } else {
                // V: 4 consecutive t in one 16B unit -> single 8B store
                const int h  = (nf - 8) * 16 + lo;
                const int tb = mq * 64 + w * 16 + hi * 4;   // tb&7 in {0,4}
                const int u  = tb >> 3;
                bf16x4 pk;
                pk[0] = (bf16)acc[mq][nf][0]; pk[1] = (bf16)acc[mq][nf][1];
                pk[2] = (bf16)acc[mq][nf][2]; pk[3] = (bf16)acc[mq][nf][3];
                *(bf16x4*)(Vb + h * 512 + ((u ^ (h & 7)) << 4) +
                           (tb & 7) * 2) = pk;
            }
        }
    }

    // Q: acc[qf][0..3] -> qfr via per-wave LDS transpose ([16][72] @65536+w*2304)
    // Pl is wave-PRIVATE: same-wave ds_write->ds_read ordered by compiler
    // lgkmcnt (no barriers needed — same pattern phase 3 already uses).
    bf16* Pl = (bf16*)(smem + 65536) + w * 1152;
    bf16x8 qfr[4][2];
    #pragma unroll
    for (int qf = 0; qf < 4; ++qf) {
        #pragma unroll
        for (int nf = 0; nf < 4; ++nf)
            #pragma unroll
            for (int i = 0; i < 4; ++i)
                Pl[(hi * 4 + i) * 72 + nf * 16 + lo] = (bf16)acc[qf][nf][i];
        #pragma unroll
        for (int ks = 0; ks < 2; ++ks)
            qfr[qf][ks] = *(const bf16x8*)(Pl + lo * 72 + ks * 32 + hi * 8);
    }
    __syncthreads();        // K/V scatter visible to all waves before phase 3

    // ---------------- phase 3: causal flash attention ----------------
    f32x4 o[4][4];
    #pragma unroll
    for (int qf = 0; qf < 4; ++qf)
        #pragma unroll
        for (int mf = 0; mf < 4; ++mf)
            o[qf][mf] = (f32x4){0.f, 0.f, 0.f, 0.f};
    float m2[4]   = {-INFINITY, -INFINITY, -INFINITY, -INFINITY};
    float lsum[4] = {0.f, 0.f, 0.f, 0.f};

    const float SC = 0.125f * 1.44269504088896340736f;  // scale * log2(e)

    #pragma unroll
    for (int kc = 0; kc < 4; ++kc) {
        bf16x8 vf[4][2];
        #pragma unroll
        for (int mf = 0; mf < 4; ++mf)
            #pragma unroll
            for (int ks = 0; ks < 2; ++ks) {
                const int h = mf * 16 + lo;             // h&7 == lo&7
                const int u = kc * 8 + ks * 4 + hi;
                vf[mf][ks] = *(const bf16x8*)(Vb + h * 512 + ((u ^ (lo & 7)) << 4));
            }

        #pragma unroll
        for (int qf = kc; qf < 4; ++qf) {
            f32x4 s[4];
            #pragma unroll
            for (int kf = 0; kf < 4; ++kf) {
                const int key = kc * 64 + kf * 16 + lo; // key&7 == lo&7
                bf16x8 k0 = *(const bf16x8*)(Kb + key * 128 + ((hi ^ (lo & 7)) << 4));
                bf16x8 k1 = *(const bf16x8*)(Kb + key * 128 + (((4 + hi) ^ (lo & 7)) << 4));
                f32x4 t = (f32x4){0.f, 0.f, 0.f, 0.f};
                t = MFMA16(k0, qfr[qf][0], t);
                t = MFMA16(k1, qfr[qf][1], t);
                s[kf] = t;
            }
            float mx = -INFINITY;
            #pragma unroll
            for (int kf = 0; kf < 4; ++kf)
                #pragma unroll
                for (int i = 0; i < 4; ++i) {
                    float v = s[kf][i] * SC;
                    if (kc == qf && (kf * 16 + hi * 4 + i) > (w * 16 + lo)) v = -INFINITY;
                    s[kf][i] = v;
                    mx = fmaxf(mx, v);
                }
            mx = fmaxf(mx, __shfl_xor(mx, 16));
            mx = fmaxf(mx, __shfl_xor(mx, 32));
            const float mnew = fmaxf(m2[qf], mx);
            const float rsc  = exp2f(m2[qf] - mnew);
            m2[qf] = mnew;

            float cs = 0.f;
            bf16x4 pk[4];
            #pragma unroll
            for (int kf = 0; kf < 4; ++kf)
                #pragma unroll
                for (int i = 0; i < 4; ++i) {
                    float p = exp2f(s[kf][i] - mnew);
                    cs += p;
                    pk[kf][i] = (bf16)p;
                }
            cs += __shfl_xor(cs, 16);
            cs += __shfl_xor(cs, 32);
            lsum[qf] = lsum[qf] * rsc + cs;

            #pragma unroll
            for (int kf = 0; kf < 4; ++kf)
                *(bf16x4*)(Pl + lo * 72 + kf * 16 + hi * 4) = pk[kf];

            #pragma unroll
            for (int mf = 0; mf < 4; ++mf) {
                o[qf][mf][0] *= rsc; o[qf][mf][1] *= rsc;
                o[qf][mf][2] *= rsc; o[qf][mf][3] *= rsc;
            }
            #pragma unroll
            for (int ks = 0; ks < 2; ++ks) {
                bf16x8 pf = *(const bf16x8*)(Pl + lo * 72 + ks * 32 + hi * 8);
                #pragma unroll
                for (int mf = 0; mf < 4; ++mf)
                    o[qf][mf] = MFMA16(vf[mf][ks], pf, o[qf][mf]);
            }
        }
    }

    // epilogue: out[b][q][h] fp32, coalesced f32x4
    #pragma unroll
    for (int qf = 0; qf < 4; ++qf) {
        const float inv = 1.0f / lsum[qf];
        const int q = qf * 64 + w * 16 + lo;
        #pragma unroll
        for (int mf = 0; mf < 4; ++mf) {
            f32x4 r4;
            r4[0] = o[qf][mf][0] * inv; r4[1] = o[qf][mf][1] * inv;
            r4[2] = o[qf][mf][2] * inv; r4[3] = o[qf][mf][3] * inv;
            *(f32x4*)(out + (b * 256 + q) * 64 + mf * 16 + hi * 4) = r4;
        }
    }
}

// ---- launcher ---------------------------------------------------------------
extern "C" void kernel_launch(void* const* d_in, const int* in_sizes, int n_in,
                              void* d_out, int out_size, void* d_ws, size_t ws_size,
                              hipStream_t stream) {
    const float* x  = (const float*)d_in[0];
    const float* Wq = (const float*)d_in[1];
    const float* Wk = (const float*)d_in[2];
    const float* Wv = (const float*)d_in[3];
    float* out = (float*)d_out;

    bf16* WTfrag = (bf16*)d_ws;

    wt_frag_kernel<<<dim3(384), dim3(256), 0, stream>>>(Wq, Wk, Wv, WTfrag);
    fused_kernel<<<dim3(512), dim3(256), 74752, stream>>>(x, WTfrag, out);
}